// Round 1
// baseline (868.788 us; speedup 1.0000x reference)
//
#include <hip/hip_runtime.h>
#include <hip/hip_bf16.h>

#define S_LEN 2048
#define HIDDEN 2048
#define NH 16
#define HD 128

typedef short short8 __attribute__((ext_vector_type(8)));
typedef short short4_t __attribute__((ext_vector_type(4)));
typedef float floatx4 __attribute__((ext_vector_type(4)));

// ---- ws layout (units of 1M = 1<<20 shorts) ------------------------------
#define MS(x) ((size_t)(x) * (size_t)(1u << 20))
#define O_XMU_HI MS(0)
#define O_XLS_HI MS(4)
#define O_XMU_LO MS(8)
#define O_WQ_HI MS(12)
#define O_WK_HI MS(16)
#define O_WQ_LO MS(20)
#define O_WK_LO MS(24)
#define O_WV MS(28)
#define O_WQS MS(32)
#define O_WKS MS(36)
#define O_WVS MS(40)
#define O_WO MS(44)
#define O_WOS MS(48)
#define O_Y2 MS(12)   // overlays Wq/Wk hi+lo (dead after q,k proj)
#define O_Y3 MS(16)
#define O_Y4 MS(20)
#define O_Y5 MS(24)
#define O_QCHI MS(52)  // tiled [h][qgrp128][k8(32)][q16][8]
#define O_KCHI MS(60)
#define O_QCLO MS(68)  // tiled, K=128
#define O_KCLO MS(72)
#define O_VT MS(76)    // tiled [h][ngrp16][kv8(256)][n16][8]
#define O_Y0F MS(84)   // fp32
#define O_Y1F MS(92)   // fp32
#define O_AOMU MS(100)
#define O_AOLS MS(104)
#define O_CK MS(108)
// KV-split partials: regions dead by fa-time (X/W staging, Y0F/Y1F)
#define O_PO0 MS(0)    // fp32 [16][2048][256] = 33.5 MB (covers XMU/XLS/XMU_LO/Y2 - dead)
#define O_PO1 MS(16)   // (covers Y3/Y4/Y5/WV - dead)
#define O_PO2 MS(84)   // (covers Y0F/Y1F - dead)
#define O_PML MS(32)   // fp32 [3][16][2048][2] m,l = 1.5 MB (covers WQS - dead)

__device__ __forceinline__ short f2bf(float f) {
  __hip_bfloat16 h = __float2bfloat16(f);  // RNE
  return __builtin_bit_cast(short, h);
}
__device__ __forceinline__ float bf2f(short s) {
  unsigned u = ((unsigned)(unsigned short)s) << 16;
  return __builtin_bit_cast(float, u);
}

typedef __attribute__((address_space(1))) const unsigned int guint;
typedef __attribute__((address_space(3))) unsigned int luint;
__device__ __forceinline__ void gll16(const void* g, void* l) {
  __builtin_amdgcn_global_load_lds((guint*)g, (luint*)l, 16, 0, 0);
}

// ---------------------------------------------------------------------------
// Conversion pass: fp32 -> bf16 hi (+ lo for z in {0,1,2}).
// ---------------------------------------------------------------------------
__global__ __launch_bounds__(256) void cvt_all(
    const float* __restrict__ xmu, const float* __restrict__ xls,
    const float* __restrict__ wq, const float* __restrict__ wk,
    const float* __restrict__ wv, const float* __restrict__ wqs,
    const float* __restrict__ wks, const float* __restrict__ wvs,
    const float* __restrict__ wo, const float* __restrict__ wos,
    short* __restrict__ Sb) {
  const int z = blockIdx.z;
  const float* src;
  size_t ho;
  size_t lof = (size_t)-1;
  switch (z) {
    case 0: src = xmu; ho = O_XMU_HI; lof = O_XMU_LO; break;
    case 1: src = wq;  ho = O_WQ_HI;  lof = O_WQ_LO;  break;
    case 2: src = wk;  ho = O_WK_HI;  lof = O_WK_LO;  break;
    case 3: src = xls; ho = O_XLS_HI; break;
    case 4: src = wv;  ho = O_WV;  break;
    case 5: src = wqs; ho = O_WQS; break;
    case 6: src = wks; ho = O_WKS; break;
    case 7: src = wvs; ho = O_WVS; break;
    case 8: src = wo;  ho = O_WO;  break;
    default: src = wos; ho = O_WOS; break;
  }
  const size_t i = ((size_t)blockIdx.x * 256 + threadIdx.x) * 4;
  const float4 v = *(const float4*)(src + i);
  short4_t h, l;
  h.x = f2bf(v.x); h.y = f2bf(v.y); h.z = f2bf(v.z); h.w = f2bf(v.w);
  *(short4_t*)(Sb + ho + i) = h;
  if (lof != (size_t)-1) {
    l.x = f2bf(v.x - bf2f(h.x));
    l.y = f2bf(v.y - bf2f(h.y));
    l.z = f2bf(v.z - bf2f(h.z));
    l.w = f2bf(v.w - bf2f(h.w));
    *(short4_t*)(Sb + lof + i) = l;
  }
}

// ---------------------------------------------------------------------------
// Plain bf16 GEMM (m97-style). modes: 0 fp32 C; 2 bf16 Cb.
// ---------------------------------------------------------------------------
__global__ __launch_bounds__(256) void gemm_plain(
    const short* __restrict__ Ah, int lda, longlong4 aoff,
    const short* __restrict__ Bh, int ldb, long long strideB,
    int K, int mode,
    float* __restrict__ C, int ldc, long long strideC,
    short* __restrict__ Cb, long long strideCb) {
  __shared__ __attribute__((aligned(16))) short As[128 * 32];
  __shared__ __attribute__((aligned(16))) short Bs[128 * 32];
  const int z = blockIdx.z;
  const long long ao = (z == 0) ? aoff.x : (z == 1) ? aoff.y : (z == 2) ? aoff.z : aoff.w;
  const short* A = Ah + ao;
  const short* B = Bh + (long long)z * strideB;
  const int m0 = blockIdx.y * 128, n0 = blockIdx.x * 128;
  const int tid = threadIdx.x, lane = tid & 63, wave = tid >> 6;
  const int wr = wave >> 1, wc = wave & 1;
  const int lr = lane >> 2;
  const int lc = (lane & 3) * 8;
  const int fr = lane & 15, koff = (lane >> 4) * 8;

  floatx4 acc[4][4];
#pragma unroll
  for (int i = 0; i < 4; ++i)
#pragma unroll
    for (int j = 0; j < 4; ++j) acc[i][j] = 0.0f;

  for (int k0 = 0; k0 < K; k0 += 32) {
#pragma unroll
    for (int j = 0; j < 2; ++j) {
      const int chunk = j * 4 + wave;
      gll16(A + (size_t)(m0 + chunk * 16 + lr) * lda + k0 + lc, &As[chunk * 512]);
      gll16(B + (size_t)(n0 + chunk * 16 + lr) * ldb + k0 + lc, &Bs[chunk * 512]);
    }
    __syncthreads();
    short8 af[4], bf[4];
#pragma unroll
    for (int i = 0; i < 4; ++i)
      af[i] = *(const short8*)&As[(wr * 64 + i * 16 + fr) * 32 + koff];
#pragma unroll
    for (int j = 0; j < 4; ++j)
      bf[j] = *(const short8*)&Bs[(wc * 64 + j * 16 + fr) * 32 + koff];
#pragma unroll
    for (int i = 0; i < 4; ++i)
#pragma unroll
      for (int j = 0; j < 4; ++j)
        acc[i][j] = __builtin_amdgcn_mfma_f32_16x16x32_bf16(af[i], bf[j], acc[i][j], 0, 0, 0);
    __syncthreads();
  }

  const int cr = (lane >> 4) * 4, cc = lane & 15;
#pragma unroll
  for (int i = 0; i < 4; ++i)
#pragma unroll
    for (int j = 0; j < 4; ++j) {
      const int rowb = m0 + wr * 64 + i * 16 + cr;
      const int col = n0 + wc * 64 + j * 16 + cc;
#pragma unroll
      for (int r = 0; r < 4; ++r) {
        const float v = acc[i][j][r];
        if (mode == 0) {
          C[(long long)z * strideC + (size_t)(rowb + r) * ldc + col] = v;
        } else {
          Cb[(long long)z * strideCb + (size_t)(rowb + r) * ldc + col] = f2bf(v);
        }
      }
    }
}

// ---------------------------------------------------------------------------
// Split-precision (bf16x3) GEMM: x3 for k<K3, plain beyond. fp32 C out.
// ---------------------------------------------------------------------------
__global__ __launch_bounds__(256) void gemm_x3(
    const short* __restrict__ Ah, const short* __restrict__ Al, int lda, int ldal,
    longlong4 aoff, longlong4 aoffl,
    const short* __restrict__ Bh, const short* __restrict__ Bl, int ldb, int ldbl,
    long long strideB, long long strideBl, int K, int K3,
    float* __restrict__ C, int ldc, long long strideC) {
  __shared__ __attribute__((aligned(16))) short As[128 * 32];
  __shared__ __attribute__((aligned(16))) short Bs[128 * 32];
  __shared__ __attribute__((aligned(16))) short Asl[128 * 32];
  __shared__ __attribute__((aligned(16))) short Bsl[128 * 32];
  const int z = blockIdx.z;
  const long long ao = (z == 0) ? aoff.x : (z == 1) ? aoff.y : (z == 2) ? aoff.z : aoff.w;
  const long long aol = (z == 0) ? aoffl.x : (z == 1) ? aoffl.y : (z == 2) ? aoffl.z : aoffl.w;
  const short* A = Ah + ao;
  const short* ALo = Al + aol;
  const short* B = Bh + (long long)z * strideB;
  const short* BLo = Bl + (long long)z * strideBl;
  const int m0 = blockIdx.y * 128, n0 = blockIdx.x * 128;
  const int tid = threadIdx.x, lane = tid & 63, wave = tid >> 6;
  const int wr = wave >> 1, wc = wave & 1;
  const int lr = lane >> 2;
  const int lc = (lane & 3) * 8;
  const int fr = lane & 15, koff = (lane >> 4) * 8;

  floatx4 acc[4][4];
#pragma unroll
  for (int i = 0; i < 4; ++i)
#pragma unroll
    for (int j = 0; j < 4; ++j) acc[i][j] = 0.0f;

  for (int k0 = 0; k0 < K; k0 += 32) {
    const bool hl = (k0 < K3);
#pragma unroll
    for (int j = 0; j < 2; ++j) {
      const int chunk = j * 4 + wave;
      gll16(A + (size_t)(m0 + chunk * 16 + lr) * lda + k0 + lc, &As[chunk * 512]);
      gll16(B + (size_t)(n0 + chunk * 16 + lr) * ldb + k0 + lc, &Bs[chunk * 512]);
      if (hl) {
        gll16(ALo + (size_t)(m0 + chunk * 16 + lr) * ldal + k0 + lc, &Asl[chunk * 512]);
        gll16(BLo + (size_t)(n0 + chunk * 16 + lr) * ldbl + k0 + lc, &Bsl[chunk * 512]);
      }
    }
    __syncthreads();
    short8 af[4], bf[4], afl[4], bfl[4];
#pragma unroll
    for (int i = 0; i < 4; ++i) {
      af[i] = *(const short8*)&As[(wr * 64 + i * 16 + fr) * 32 + koff];
      if (hl) afl[i] = *(const short8*)&Asl[(wr * 64 + i * 16 + fr) * 32 + koff];
    }
#pragma unroll
    for (int j = 0; j < 4; ++j) {
      bf[j] = *(const short8*)&Bs[(wc * 64 + j * 16 + fr) * 32 + koff];
      if (hl) bfl[j] = *(const short8*)&Bsl[(wc * 64 + j * 16 + fr) * 32 + koff];
    }
#pragma unroll
    for (int i = 0; i < 4; ++i)
#pragma unroll
      for (int j = 0; j < 4; ++j) {
        acc[i][j] = __builtin_amdgcn_mfma_f32_16x16x32_bf16(af[i], bf[j], acc[i][j], 0, 0, 0);
        if (hl) {
          acc[i][j] = __builtin_amdgcn_mfma_f32_16x16x32_bf16(af[i], bfl[j], acc[i][j], 0, 0, 0);
          acc[i][j] = __builtin_amdgcn_mfma_f32_16x16x32_bf16(afl[i], bf[j], acc[i][j], 0, 0, 0);
        }
      }
    __syncthreads();
  }

  const int cr = (lane >> 4) * 4, cc = lane & 15;
#pragma unroll
  for (int i = 0; i < 4; ++i)
#pragma unroll
    for (int j = 0; j < 4; ++j) {
      const int rowb = m0 + wr * 64 + i * 16 + cr;
      const int col = n0 + wc * 64 + j * 16 + cc;
#pragma unroll
      for (int r = 0; r < 4; ++r)
        C[(long long)z * strideC + (size_t)(rowb + r) * ldc + col] = acc[i][j][r];
    }
}

// ---------------------------------------------------------------------------
// RoPE + expm1 + QC/KC tiled hi/lo build + ck.
// Tiled layout: elem (s,k) -> grp=(h*128+(s>>4)): grp*K16 + (k>>3)*128 + (s&15)*8 + (k&7)
// ---------------------------------------------------------------------------
__global__ __launch_bounds__(128) void build_qk(
    const float* __restrict__ Yq, const float* __restrict__ Yk,
    const short* __restrict__ Yqs, const short* __restrict__ Yks,
    const float* __restrict__ cosp, const float* __restrict__ sinp,
    short* __restrict__ QChi, short* __restrict__ QClo,
    short* __restrict__ KChi, short* __restrict__ KClo, float* __restrict__ ck) {
  const int s = blockIdx.x;
  const int h = blockIdx.y;
  const int d = threadIdx.x;  // 0..127
  const size_t base = (size_t)s * HIDDEN + h * HD;
  const float c = cosp[s * HD + d];
  const float sn = sinp[s * HD + d];
  const float q = Yq[base + d];
  const float qp = Yq[base + (d ^ 64)];
  const float k = Yk[base + d];
  const float kp = Yk[base + (d ^ 64)];
  const float qr = q * c + ((d < 64) ? -qp : qp) * sn;
  const float kr = k * c + ((d < 64) ? -kp : kp) * sn;
  const float aq = expm1f(0.5f * bf2f(Yqs[base + d]));
  const float ak = expm1f(0.5f * bf2f(Yks[base + d]));
  const size_t grp = (size_t)h * 128 + (s >> 4);
  const int s16 = s & 15;
  const size_t o_hi_d = grp * 4096 + (d >> 3) * 128 + s16 * 8 + (d & 7);
  const size_t o_hi_a = grp * 4096 + ((128 + d) >> 3) * 128 + s16 * 8 + (d & 7);
  const size_t o_lo_d = grp * 2048 + (d >> 3) * 128 + s16 * 8 + (d & 7);
  const short qh = f2bf(qr), kh = f2bf(kr);
  QChi[o_hi_d] = qh;
  QClo[o_lo_d] = f2bf(qr - bf2f(qh));
  QChi[o_hi_a] = f2bf(aq);
  KChi[o_hi_d] = kh;
  KClo[o_lo_d] = f2bf(kr - bf2f(kh));
  KChi[o_hi_a] = f2bf(ak);

  float val = kr * kr + ak * ak;
#pragma unroll
  for (int off = 32; off > 0; off >>= 1) val += __shfl_down(val, off);
  __shared__ float red[2];
  if ((d & 63) == 0) red[d >> 6] = val;
  __syncthreads();
  if (d == 0) ck[(size_t)h * S_LEN + s] = red[0] + red[1];
}

// ---------------------------------------------------------------------------
// VT tiled [h][ngrp16][kv8(256)][n16][8]: n<128 -> v_mu, else v_ls
// ---------------------------------------------------------------------------
__global__ __launch_bounds__(256) void build_vt(const short* __restrict__ Yv,
                                                const short* __restrict__ Yvs,
                                                short* __restrict__ VT) {
  __shared__ short tile[32][33];
  const int s0 = blockIdx.x * 32;
  const int n0 = blockIdx.y * 32;  // never straddles 128
  const int h = blockIdx.z;
  const int tid = threadIdx.x;
  const int tx = tid & 31;
  const int ty = tid >> 5;
  const short* src = (n0 < HD) ? Yv : Yvs;
  const int c0 = n0 & (HD - 1);
#pragma unroll
  for (int r = ty; r < 32; r += 8)
    tile[r][tx] = src[(size_t)(s0 + r) * HIDDEN + h * HD + c0 + tx];
  __syncthreads();
  // 128 chunks: nl (32) x s8 (4); threads 0..127
  if (tid < 128) {
    const int nl = tid >> 2;
    const int s8 = tid & 3;
    short8 v;
#pragma unroll
    for (int e = 0; e < 8; ++e) v[e] = tile[s8 * 8 + e][nl];
    const int n = n0 + nl;
    const int kv8 = (s0 >> 3) + s8;
    const size_t off = (size_t)h * 524288 + (size_t)(n >> 4) * 32768 + (size_t)kv8 * 128 +
                       (n & 15) * 8;
    *(short8*)&VT[off] = v;
  }
}

// ---------------------------------------------------------------------------
// Fused flash attention, KV-split 3 ways (flash-decoding style).
// Grid (32 qtiles, 16 heads, 3 kv-splits), 256 threads. Wave w owns 16 q-rows.
// Each split writes unnormalized fp32 partial O + per-row (m,l); fa_combine merges.
// ---------------------------------------------------------------------------
__global__ __launch_bounds__(256) void fa_kernel(
    const short* __restrict__ QChi, const short* __restrict__ QClo,
    const short* __restrict__ KChi, const short* __restrict__ KClo,
    const short* __restrict__ VT, const float* __restrict__ ck,
    const float* __restrict__ tau,
    float* __restrict__ PO0, float* __restrict__ PO1, float* __restrict__ PO2,
    float* __restrict__ PML) {
  __shared__ __attribute__((aligned(16))) short kchi[8192];  // [g2][ks8][1KB-chunk]
  __shared__ __attribute__((aligned(16))) short kclo[4096];  // [g2][ks4][1KB]
  __shared__ __attribute__((aligned(16))) short vt[8192];    // [ngrp16][1KB]
  __shared__ __attribute__((aligned(16))) short patch[2048]; // 4 waves x 1KB

  const int qt = blockIdx.x;
  const int h = blockIdx.y;
  const int z = blockIdx.z;
  const int t0 = (z == 0) ? 0 : (z == 1) ? 22 : 43;
  const int t1 = (z == 0) ? 22 : (z == 1) ? 43 : 64;
  const int tid = threadIdx.x;
  const int lane = tid & 63;
  const int w = tid >> 6;
  const int qgrp = qt * 4 + w;
  const float inv = 1.0f / (fabsf(tau[0]) + 1e-6f);

  const short* QChi_h = QChi + (size_t)h * 524288;
  const short* QClo_h = QClo + (size_t)h * 262144;
  const short* KChi_h = KChi + (size_t)h * 524288;
  const short* KClo_h = KClo + (size_t)h * 262144;
  const short* VT_h = VT + (size_t)h * 524288;
  const float* ckh = ck + (size_t)h * S_LEN;

  // Q fragments in registers
  short8 qhi[8], qlo[4];
#pragma unroll
  for (int ks = 0; ks < 8; ++ks)
    qhi[ks] = *(const short8*)&QChi_h[(size_t)qgrp * 4096 + ks * 512 + lane * 8];
#pragma unroll
  for (int ks = 0; ks < 4; ++ks)
    qlo[ks] = *(const short8*)&QClo_h[(size_t)qgrp * 2048 + ks * 512 + lane * 8];

  floatx4 o[16];
#pragma unroll
  for (int nf = 0; nf < 16; ++nf) o[nf] = 0.0f;
  float m_[4], l_[4];
#pragma unroll
  for (int r = 0; r < 4; ++r) { m_[r] = -1e30f; l_[r] = 0.0f; }

  short* patchw = &patch[w * 512];

  for (int t = t0; t < t1; ++t) {
    // ---- stage K/V tiles (kv = t*32 .. +32) ----
#pragma unroll
    for (int i = 0; i < 4; ++i) {
      const int c = w * 4 + i;
      gll16(KChi_h + (size_t)(2 * t + (c >> 3)) * 4096 + (c & 7) * 512 + lane * 8,
            &kchi[c * 512]);
    }
#pragma unroll
    for (int i = 0; i < 2; ++i) {
      const int c = w * 2 + i;
      gll16(KClo_h + (size_t)(2 * t + (c >> 2)) * 2048 + (c & 3) * 512 + lane * 8,
            &kclo[c * 512]);
    }
#pragma unroll
    for (int i = 0; i < 4; ++i) {
      const int c = w * 4 + i;
      gll16(VT_h + (size_t)c * 32768 + t * 512 + lane * 8, &vt[c * 512]);
    }
    __syncthreads();

    // ---- S = Q·K^T (16q x 32kv), x3 on first 128 of K ----
    floatx4 s0 = 0.0f, s1 = 0.0f;
#pragma unroll
    for (int ks = 0; ks < 8; ++ks) {
      const short8 b0 = *(const short8*)&kchi[ks * 512 + lane * 8];
      const short8 b1 = *(const short8*)&kchi[(8 + ks) * 512 + lane * 8];
      s0 = __builtin_amdgcn_mfma_f32_16x16x32_bf16(qhi[ks], b0, s0, 0, 0, 0);
      s1 = __builtin_amdgcn_mfma_f32_16x16x32_bf16(qhi[ks], b1, s1, 0, 0, 0);
    }
#pragma unroll
    for (int ks = 0; ks < 4; ++ks) {
      const short8 bl0 = *(const short8*)&kclo[ks * 512 + lane * 8];
      const short8 bl1 = *(const short8*)&kclo[(4 + ks) * 512 + lane * 8];
      s0 = __builtin_amdgcn_mfma_f32_16x16x32_bf16(qhi[ks], bl0, s0, 0, 0, 0);
      s1 = __builtin_amdgcn_mfma_f32_16x16x32_bf16(qhi[ks], bl1, s1, 0, 0, 0);
      const short8 b0 = *(const short8*)&kchi[ks * 512 + lane * 8];
      const short8 b1 = *(const short8*)&kchi[(8 + ks) * 512 + lane * 8];
      s0 = __builtin_amdgcn_mfma_f32_16x16x32_bf16(qlo[ks], b0, s0, 0, 0, 0);
      s1 = __builtin_amdgcn_mfma_f32_16x16x32_bf16(qlo[ks], b1, s1, 0, 0, 0);
    }

    // ---- online softmax (C-layout: col=lane&15, row=(lane>>4)*4+r) ----
    const float ck0 = ckh[t * 32 + (lane & 15)];
    const float ck1 = ckh[t * 32 + 16 + (lane & 15)];
    float p0[4], p1[4], aph[4];
#pragma unroll
    for (int r = 0; r < 4; ++r) {
      const float L0 = (2.0f * s0[r] - ck0) * inv;
      const float L1 = (2.0f * s1[r] - ck1) * inv;
      float mx = fmaxf(L0, L1);
      mx = fmaxf(mx, __shfl_xor(mx, 1));
      mx = fmaxf(mx, __shfl_xor(mx, 2));
      mx = fmaxf(mx, __shfl_xor(mx, 4));
      mx = fmaxf(mx, __shfl_xor(mx, 8));
      const float mnew = fmaxf(m_[r], mx);
      const float alpha = __expf(m_[r] - mnew);
      m_[r] = mnew;
      p0[r] = __expf(L0 - mnew);
      p1[r] = __expf(L1 - mnew);
      float sum = p0[r] + p1[r];
      sum += __shfl_xor(sum, 1);
      sum += __shfl_xor(sum, 2);
      sum += __shfl_xor(sum, 4);
      sum += __shfl_xor(sum, 8);
      l_[r] = l_[r] * alpha + sum;
      aph[r] = alpha;
    }
#pragma unroll
    for (int nf = 0; nf < 16; ++nf)
#pragma unroll
      for (int r = 0; r < 4; ++r) o[nf][r] *= aph[r];

    // ---- P (C-layout) -> A-frag layout via wave-private LDS patch ----
    {
      const int row = (lane >> 4) * 4;
      const int c0i = lane & 15;
      const int c1i = 16 + (lane & 15);
#pragma unroll
      for (int r = 0; r < 4; ++r) {
        patchw[(c0i >> 3) * 128 + (row + r) * 8 + (c0i & 7)] = f2bf(p0[r]);
        patchw[(c1i >> 3) * 128 + (row + r) * 8 + (c1i & 7)] = f2bf(p1[r]);
      }
    }
    asm volatile("s_waitcnt lgkmcnt(0)\n" ::: "memory");
    const short8 pa = *(const short8*)&patchw[lane * 8];

    // ---- O += P·V (16q x 256n, K=32) ----
#pragma unroll
    for (int nf = 0; nf < 16; ++nf) {
      const short8 vf = *(const short8*)&vt[nf * 512 + lane * 8];
      o[nf] = __builtin_amdgcn_mfma_f32_16x16x32_bf16(pa, vf, o[nf], 0, 0, 0);
    }
    __syncthreads();
  }

  // ---- epilogue: write unnormalized fp32 partials + (m,l) per row ----
  float* PO = (z == 0) ? PO0 : (z == 1) ? PO1 : PO2;
  const int qbase = qgrp * 16 + (lane >> 4) * 4;
#pragma unroll
  for (int nf = 0; nf < 16; ++nf) {
    const int n = nf * 16 + (lane & 15);
#pragma unroll
    for (int r = 0; r < 4; ++r)
      PO[((size_t)h * S_LEN + qbase + r) * 256 + n] = o[nf][r];
  }
  if ((lane & 15) == 0) {
#pragma unroll
    for (int r = 0; r < 4; ++r) {
      float2 v;
      v.x = m_[r];
      v.y = l_[r];
      *(float2*)&PML[((size_t)(z * 16 + h) * S_LEN + qbase + r) * 2] = v;
    }
  }
}

// ---------------------------------------------------------------------------
// Merge the 3 KV-split partials: O = sum_z exp(m_z-M) O_z / sum_z exp(m_z-M) l_z
// One thread per (h,q,n4-group-of-4). Writes bf16 AOmu/AOls (linear layout).
// ---------------------------------------------------------------------------
__global__ __launch_bounds__(256) void fa_combine(
    const float* __restrict__ PO0, const float* __restrict__ PO1,
    const float* __restrict__ PO2, const float* __restrict__ PML,
    short* __restrict__ AOmu, short* __restrict__ AOls) {
  const size_t idx = (size_t)blockIdx.x * 256 + threadIdx.x;  // 16*2048*64
  const size_t hq = idx >> 6;                                 // h*2048+q
  const int n4 = (int)(idx & 63) << 2;
  const int h = (int)(hq >> 11);
  const int q = (int)(hq & 2047);
  const float2* PML2 = (const float2*)PML;
  const float2 a = PML2[hq];
  const float2 b = PML2[32768 + hq];
  const float2 c = PML2[65536 + hq];
  const float M = fmaxf(fmaxf(a.x, b.x), c.x);
  const float w0 = __expf(a.x - M);
  const float w1 = __expf(b.x - M);
  const float w2 = __expf(c.x - M);
  const float invl = 1.0f / (w0 * a.y + w1 * b.y + w2 * c.y);
  const float4 p0 = *(const float4*)(PO0 + hq * 256 + n4);
  const float4 p1 = *(const float4*)(PO1 + hq * 256 + n4);
  const float4 p2 = *(const float4*)(PO2 + hq * 256 + n4);
  short4_t r;
  r.x = f2bf((w0 * p0.x + w1 * p1.x + w2 * p2.x) * invl);
  r.y = f2bf((w0 * p0.y + w1 * p1.y + w2 * p2.y) * invl);
  r.z = f2bf((w0 * p0.z + w1 * p1.z + w2 * p2.z) * invl);
  r.w = f2bf((w0 * p0.w + w1 * p1.w + w2 * p2.w) * invl);
  short* dst = (n4 < HD) ? AOmu : AOls;
  *(short4_t*)&dst[(size_t)q * HIDDEN + h * HD + (n4 & (HD - 1))] = r;
}

// ---------------------------------------------------------------------------
extern "C" void kernel_launch(void* const* d_in, const int* in_sizes, int n_in,
                              void* d_out, int out_size, void* d_ws, size_t ws_size,
                              hipStream_t stream) {
  (void)in_sizes; (void)n_in; (void)out_size; (void)ws_size;
  const float* Xmu = (const float*)d_in[0];
  const float* Xls = (const float*)d_in[1];
  const float* cosp = (const float*)d_in[2];
  const float* sinp = (const float*)d_in[3];
  const float* Wq_mu = (const float*)d_in[4];
  const float* Wk_mu = (const float*)d_in[5];
  const float* Wv_mu = (const float*)d_in[6];
  const float* Wo_mu = (const float*)d_in[7];
  const float* Wq_s = (const float*)d_in[8];
  const float* Wk_s = (const float*)d_in[9];
  const float* Wv_s = (const float*)d_in[10];
  const float* Wo_s = (const float*)d_in[11];
  const float* tau = (const float*)d_in[12];

  float* out = (float*)d_out;
  short* S = (short*)d_ws;
  const longlong4 Z4 = {0, 0, 0, 0};
  const long long M4 = (long long)MS(4);

  // 1. conversions
  cvt_all<<<dim3(4096, 1, 10), 256, 0, stream>>>(Xmu, Xls, Wq_mu, Wk_mu, Wv_mu, Wq_s,
                                                 Wk_s, Wv_s, Wo_mu, Wo_s, S);

  // 2. q,k mu projections (x3, full K) -> Y0f/Y1f fp32
  gemm_x3<<<dim3(16, 16, 2), 256, 0, stream>>>(
      S + O_XMU_HI, S + O_XMU_LO, HIDDEN, HIDDEN, Z4, Z4,
      S + O_WQ_HI, S + O_WQ_LO, HIDDEN, HIDDEN, M4, M4, HIDDEN, HIDDEN,
      (float*)(S + O_Y0F), HIDDEN, 4194304);

  // 3. v_mu + sigma projections (plain, z=4) -> Y2..Y5 bf16
  {
    longlong4 ao = {0, (long long)MS(4), (long long)MS(4), (long long)MS(4)};
    gemm_plain<<<dim3(16, 16, 4), 256, 0, stream>>>(
        S + O_XMU_HI, HIDDEN, ao, S + O_WV, HIDDEN, M4, HIDDEN, 2,
        nullptr, HIDDEN, 0, S + O_Y2, M4);
  }

  // 4. build tiled QC/KC + ck, tiled VT
  build_qk<<<dim3(S_LEN, NH), 128, 0, stream>>>(
      (const float*)(S + O_Y0F), (const float*)(S + O_Y1F), S + O_Y3, S + O_Y4,
      cosp, sinp, S + O_QCHI, S + O_QCLO, S + O_KCHI, S + O_KCLO,
      (float*)(S + O_CK));
  build_vt<<<dim3(S_LEN / 32, 256 / 32, NH), 256, 0, stream>>>(S + O_Y2, S + O_Y5,
                                                               S + O_VT);

  // 5. fused flash attention, KV-split x3 -> fp32 partials
  fa_kernel<<<dim3(32, NH, 3), 256, 0, stream>>>(
      S + O_QCHI, S + O_QCLO, S + O_KCHI, S + O_KCLO, S + O_VT,
      (const float*)(S + O_CK), tau,
      (float*)(S + O_PO0), (float*)(S + O_PO1), (float*)(S + O_PO2),
      (float*)(S + O_PML));

  // 5b. merge partials -> AOmu/AOls bf16
  fa_combine<<<dim3(8192), 256, 0, stream>>>(
      (const float*)(S + O_PO0), (const float*)(S + O_PO1),
      (const float*)(S + O_PO2), (const float*)(S + O_PML),
      S + O_AOMU, S + O_AOLS);

  // 6. output projections (z=2) -> d_out fp32
  {
    longlong4 ao = {0, (long long)MS(4), 0, 0};
    gemm_plain<<<dim3(16, 16, 2), 256, 0, stream>>>(
        S + O_AOMU, HIDDEN, ao, S + O_WO, HIDDEN, M4, HIDDEN, 0,
        out, HIDDEN, 4194304, nullptr, 0);
  }
}

// Round 2
// 689.641 us; speedup vs baseline: 1.2598x; 1.2598x over previous
//
#include <hip/hip_runtime.h>
#include <hip/hip_bf16.h>

#define S_LEN 2048
#define HIDDEN 2048
#define NH 16
#define HD 128

typedef short short8 __attribute__((ext_vector_type(8)));
typedef short short4_t __attribute__((ext_vector_type(4)));
typedef float floatx4 __attribute__((ext_vector_type(4)));

// ---- ws layout (units of 1M = 1<<20 shorts) ------------------------------
#define MS(x) ((size_t)(x) * (size_t)(1u << 20))
#define O_XMU_HI MS(0)
#define O_XLS_HI MS(4)
#define O_XMU_LO MS(8)
#define O_WQ_HI MS(12)
#define O_WK_HI MS(16)
#define O_WQ_LO MS(20)
#define O_WK_LO MS(24)
#define O_WV MS(28)
#define O_WQS MS(32)
#define O_WKS MS(36)
#define O_WVS MS(40)
#define O_WO MS(44)
#define O_WOS MS(48)
#define O_Y2 MS(12)   // overlays Wq/Wk hi+lo (dead after q,k proj)
#define O_Y3 MS(16)
#define O_Y4 MS(20)
#define O_Y5 MS(24)
#define O_QCHI MS(52)  // tiled [h][qgrp128][k8(32)][q16][8]
#define O_KCHI MS(60)
#define O_QCLO MS(68)  // tiled, K=128
#define O_KCLO MS(72)
#define O_VT MS(76)    // tiled [h][ngrp16][kv8(256)][n16][8]
#define O_Y0F MS(84)   // fp32
#define O_Y1F MS(92)   // fp32
#define O_AOMU MS(100)
#define O_AOLS MS(104)
#define O_CK MS(108)

__device__ __forceinline__ short f2bf(float f) {
  __hip_bfloat16 h = __float2bfloat16(f);  // RNE
  return __builtin_bit_cast(short, h);
}
__device__ __forceinline__ float bf2f(short s) {
  unsigned u = ((unsigned)(unsigned short)s) << 16;
  return __builtin_bit_cast(float, u);
}

typedef __attribute__((address_space(1))) const unsigned int guint;
typedef __attribute__((address_space(3))) unsigned int luint;
__device__ __forceinline__ void gll16(const void* g, void* l) {
  __builtin_amdgcn_global_load_lds((guint*)g, (luint*)l, 16, 0, 0);
}

// ---------------------------------------------------------------------------
// Conversion pass: fp32 -> bf16 hi (+ lo for z in {0,1,2}).
// ---------------------------------------------------------------------------
__global__ __launch_bounds__(256) void cvt_all(
    const float* __restrict__ xmu, const float* __restrict__ xls,
    const float* __restrict__ wq, const float* __restrict__ wk,
    const float* __restrict__ wv, const float* __restrict__ wqs,
    const float* __restrict__ wks, const float* __restrict__ wvs,
    const float* __restrict__ wo, const float* __restrict__ wos,
    short* __restrict__ Sb) {
  const int z = blockIdx.z;
  const float* src;
  size_t ho;
  size_t lof = (size_t)-1;
  switch (z) {
    case 0: src = xmu; ho = O_XMU_HI; lof = O_XMU_LO; break;
    case 1: src = wq;  ho = O_WQ_HI;  lof = O_WQ_LO;  break;
    case 2: src = wk;  ho = O_WK_HI;  lof = O_WK_LO;  break;
    case 3: src = xls; ho = O_XLS_HI; break;
    case 4: src = wv;  ho = O_WV;  break;
    case 5: src = wqs; ho = O_WQS; break;
    case 6: src = wks; ho = O_WKS; break;
    case 7: src = wvs; ho = O_WVS; break;
    case 8: src = wo;  ho = O_WO;  break;
    default: src = wos; ho = O_WOS; break;
  }
  const size_t i = ((size_t)blockIdx.x * 256 + threadIdx.x) * 4;
  const float4 v = *(const float4*)(src + i);
  short4_t h, l;
  h.x = f2bf(v.x); h.y = f2bf(v.y); h.z = f2bf(v.z); h.w = f2bf(v.w);
  *(short4_t*)(Sb + ho + i) = h;
  if (lof != (size_t)-1) {
    l.x = f2bf(v.x - bf2f(h.x));
    l.y = f2bf(v.y - bf2f(h.y));
    l.z = f2bf(v.z - bf2f(h.z));
    l.w = f2bf(v.w - bf2f(h.w));
    *(short4_t*)(Sb + lof + i) = l;
  }
}

// ---------------------------------------------------------------------------
// Plain bf16 GEMM (m97-style). modes: 0 fp32 C; 2 bf16 Cb.
// ---------------------------------------------------------------------------
__global__ __launch_bounds__(256) void gemm_plain(
    const short* __restrict__ Ah, int lda, longlong4 aoff,
    const short* __restrict__ Bh, int ldb, long long strideB,
    int K, int mode,
    float* __restrict__ C, int ldc, long long strideC,
    short* __restrict__ Cb, long long strideCb) {
  __shared__ __attribute__((aligned(16))) short As[128 * 32];
  __shared__ __attribute__((aligned(16))) short Bs[128 * 32];
  const int z = blockIdx.z;
  const long long ao = (z == 0) ? aoff.x : (z == 1) ? aoff.y : (z == 2) ? aoff.z : aoff.w;
  const short* A = Ah + ao;
  const short* B = Bh + (long long)z * strideB;
  const int m0 = blockIdx.y * 128, n0 = blockIdx.x * 128;
  const int tid = threadIdx.x, lane = tid & 63, wave = tid >> 6;
  const int wr = wave >> 1, wc = wave & 1;
  const int lr = lane >> 2;
  const int lc = (lane & 3) * 8;
  const int fr = lane & 15, koff = (lane >> 4) * 8;

  floatx4 acc[4][4];
#pragma unroll
  for (int i = 0; i < 4; ++i)
#pragma unroll
    for (int j = 0; j < 4; ++j) acc[i][j] = 0.0f;

  for (int k0 = 0; k0 < K; k0 += 32) {
#pragma unroll
    for (int j = 0; j < 2; ++j) {
      const int chunk = j * 4 + wave;
      gll16(A + (size_t)(m0 + chunk * 16 + lr) * lda + k0 + lc, &As[chunk * 512]);
      gll16(B + (size_t)(n0 + chunk * 16 + lr) * ldb + k0 + lc, &Bs[chunk * 512]);
    }
    __syncthreads();
    short8 af[4], bf[4];
#pragma unroll
    for (int i = 0; i < 4; ++i)
      af[i] = *(const short8*)&As[(wr * 64 + i * 16 + fr) * 32 + koff];
#pragma unroll
    for (int j = 0; j < 4; ++j)
      bf[j] = *(const short8*)&Bs[(wc * 64 + j * 16 + fr) * 32 + koff];
#pragma unroll
    for (int i = 0; i < 4; ++i)
#pragma unroll
      for (int j = 0; j < 4; ++j)
        acc[i][j] = __builtin_amdgcn_mfma_f32_16x16x32_bf16(af[i], bf[j], acc[i][j], 0, 0, 0);
    __syncthreads();
  }

  const int cr = (lane >> 4) * 4, cc = lane & 15;
#pragma unroll
  for (int i = 0; i < 4; ++i)
#pragma unroll
    for (int j = 0; j < 4; ++j) {
      const int rowb = m0 + wr * 64 + i * 16 + cr;
      const int col = n0 + wc * 64 + j * 16 + cc;
#pragma unroll
      for (int r = 0; r < 4; ++r) {
        const float v = acc[i][j][r];
        if (mode == 0) {
          C[(long long)z * strideC + (size_t)(rowb + r) * ldc + col] = v;
        } else {
          Cb[(long long)z * strideCb + (size_t)(rowb + r) * ldc + col] = f2bf(v);
        }
      }
    }
}

// ---------------------------------------------------------------------------
// Split-precision (bf16x3) GEMM: x3 for k<K3, plain beyond. fp32 C out.
// ---------------------------------------------------------------------------
__global__ __launch_bounds__(256) void gemm_x3(
    const short* __restrict__ Ah, const short* __restrict__ Al, int lda, int ldal,
    longlong4 aoff, longlong4 aoffl,
    const short* __restrict__ Bh, const short* __restrict__ Bl, int ldb, int ldbl,
    long long strideB, long long strideBl, int K, int K3,
    float* __restrict__ C, int ldc, long long strideC) {
  __shared__ __attribute__((aligned(16))) short As[128 * 32];
  __shared__ __attribute__((aligned(16))) short Bs[128 * 32];
  __shared__ __attribute__((aligned(16))) short Asl[128 * 32];
  __shared__ __attribute__((aligned(16))) short Bsl[128 * 32];
  const int z = blockIdx.z;
  const long long ao = (z == 0) ? aoff.x : (z == 1) ? aoff.y : (z == 2) ? aoff.z : aoff.w;
  const long long aol = (z == 0) ? aoffl.x : (z == 1) ? aoffl.y : (z == 2) ? aoffl.z : aoffl.w;
  const short* A = Ah + ao;
  const short* ALo = Al + aol;
  const short* B = Bh + (long long)z * strideB;
  const short* BLo = Bl + (long long)z * strideBl;
  const int m0 = blockIdx.y * 128, n0 = blockIdx.x * 128;
  const int tid = threadIdx.x, lane = tid & 63, wave = tid >> 6;
  const int wr = wave >> 1, wc = wave & 1;
  const int lr = lane >> 2;
  const int lc = (lane & 3) * 8;
  const int fr = lane & 15, koff = (lane >> 4) * 8;

  floatx4 acc[4][4];
#pragma unroll
  for (int i = 0; i < 4; ++i)
#pragma unroll
    for (int j = 0; j < 4; ++j) acc[i][j] = 0.0f;

  for (int k0 = 0; k0 < K; k0 += 32) {
    const bool hl = (k0 < K3);
#pragma unroll
    for (int j = 0; j < 2; ++j) {
      const int chunk = j * 4 + wave;
      gll16(A + (size_t)(m0 + chunk * 16 + lr) * lda + k0 + lc, &As[chunk * 512]);
      gll16(B + (size_t)(n0 + chunk * 16 + lr) * ldb + k0 + lc, &Bs[chunk * 512]);
      if (hl) {
        gll16(ALo + (size_t)(m0 + chunk * 16 + lr) * ldal + k0 + lc, &Asl[chunk * 512]);
        gll16(BLo + (size_t)(n0 + chunk * 16 + lr) * ldbl + k0 + lc, &Bsl[chunk * 512]);
      }
    }
    __syncthreads();
    short8 af[4], bf[4], afl[4], bfl[4];
#pragma unroll
    for (int i = 0; i < 4; ++i) {
      af[i] = *(const short8*)&As[(wr * 64 + i * 16 + fr) * 32 + koff];
      if (hl) afl[i] = *(const short8*)&Asl[(wr * 64 + i * 16 + fr) * 32 + koff];
    }
#pragma unroll
    for (int j = 0; j < 4; ++j) {
      bf[j] = *(const short8*)&Bs[(wc * 64 + j * 16 + fr) * 32 + koff];
      if (hl) bfl[j] = *(const short8*)&Bsl[(wc * 64 + j * 16 + fr) * 32 + koff];
    }
#pragma unroll
    for (int i = 0; i < 4; ++i)
#pragma unroll
      for (int j = 0; j < 4; ++j) {
        acc[i][j] = __builtin_amdgcn_mfma_f32_16x16x32_bf16(af[i], bf[j], acc[i][j], 0, 0, 0);
        if (hl) {
          acc[i][j] = __builtin_amdgcn_mfma_f32_16x16x32_bf16(af[i], bfl[j], acc[i][j], 0, 0, 0);
          acc[i][j] = __builtin_amdgcn_mfma_f32_16x16x32_bf16(afl[i], bf[j], acc[i][j], 0, 0, 0);
        }
      }
    __syncthreads();
  }

  const int cr = (lane >> 4) * 4, cc = lane & 15;
#pragma unroll
  for (int i = 0; i < 4; ++i)
#pragma unroll
    for (int j = 0; j < 4; ++j) {
      const int rowb = m0 + wr * 64 + i * 16 + cr;
      const int col = n0 + wc * 64 + j * 16 + cc;
#pragma unroll
      for (int r = 0; r < 4; ++r)
        C[(long long)z * strideC + (size_t)(rowb + r) * ldc + col] = acc[i][j][r];
    }
}

// ---------------------------------------------------------------------------
// RoPE + expm1 + QC/KC tiled hi/lo build + ck.
// Tiled layout: elem (s,k) -> grp=(h*128+(s>>4)): grp*K16 + (k>>3)*128 + (s&15)*8 + (k&7)
// ---------------------------------------------------------------------------
__global__ __launch_bounds__(128) void build_qk(
    const float* __restrict__ Yq, const float* __restrict__ Yk,
    const short* __restrict__ Yqs, const short* __restrict__ Yks,
    const float* __restrict__ cosp, const float* __restrict__ sinp,
    short* __restrict__ QChi, short* __restrict__ QClo,
    short* __restrict__ KChi, short* __restrict__ KClo, float* __restrict__ ck) {
  const int s = blockIdx.x;
  const int h = blockIdx.y;
  const int d = threadIdx.x;  // 0..127
  const size_t base = (size_t)s * HIDDEN + h * HD;
  const float c = cosp[s * HD + d];
  const float sn = sinp[s * HD + d];
  const float q = Yq[base + d];
  const float qp = Yq[base + (d ^ 64)];
  const float k = Yk[base + d];
  const float kp = Yk[base + (d ^ 64)];
  const float qr = q * c + ((d < 64) ? -qp : qp) * sn;
  const float kr = k * c + ((d < 64) ? -kp : kp) * sn;
  const float aq = expm1f(0.5f * bf2f(Yqs[base + d]));
  const float ak = expm1f(0.5f * bf2f(Yks[base + d]));
  const size_t grp = (size_t)h * 128 + (s >> 4);
  const int s16 = s & 15;
  const size_t o_hi_d = grp * 4096 + (d >> 3) * 128 + s16 * 8 + (d & 7);
  const size_t o_hi_a = grp * 4096 + ((128 + d) >> 3) * 128 + s16 * 8 + (d & 7);
  const size_t o_lo_d = grp * 2048 + (d >> 3) * 128 + s16 * 8 + (d & 7);
  const short qh = f2bf(qr), kh = f2bf(kr);
  QChi[o_hi_d] = qh;
  QClo[o_lo_d] = f2bf(qr - bf2f(qh));
  QChi[o_hi_a] = f2bf(aq);
  KChi[o_hi_d] = kh;
  KClo[o_lo_d] = f2bf(kr - bf2f(kh));
  KChi[o_hi_a] = f2bf(ak);

  float val = kr * kr + ak * ak;
#pragma unroll
  for (int off = 32; off > 0; off >>= 1) val += __shfl_down(val, off);
  __shared__ float red[2];
  if ((d & 63) == 0) red[d >> 6] = val;
  __syncthreads();
  if (d == 0) ck[(size_t)h * S_LEN + s] = red[0] + red[1];
}

// ---------------------------------------------------------------------------
// VT tiled [h][ngrp16][kv8(256)][n16][8]: n<128 -> v_mu, else v_ls
// ---------------------------------------------------------------------------
__global__ __launch_bounds__(256) void build_vt(const short* __restrict__ Yv,
                                                const short* __restrict__ Yvs,
                                                short* __restrict__ VT) {
  __shared__ short tile[32][33];
  const int s0 = blockIdx.x * 32;
  const int n0 = blockIdx.y * 32;  // never straddles 128
  const int h = blockIdx.z;
  const int tid = threadIdx.x;
  const int tx = tid & 31;
  const int ty = tid >> 5;
  const short* src = (n0 < HD) ? Yv : Yvs;
  const int c0 = n0 & (HD - 1);
#pragma unroll
  for (int r = ty; r < 32; r += 8)
    tile[r][tx] = src[(size_t)(s0 + r) * HIDDEN + h * HD + c0 + tx];
  __syncthreads();
  // 128 chunks: nl (32) x s8 (4); threads 0..127
  if (tid < 128) {
    const int nl = tid >> 2;
    const int s8 = tid & 3;
    short8 v;
#pragma unroll
    for (int e = 0; e < 8; ++e) v[e] = tile[s8 * 8 + e][nl];
    const int n = n0 + nl;
    const int kv8 = (s0 >> 3) + s8;
    const size_t off = (size_t)h * 524288 + (size_t)(n >> 4) * 32768 + (size_t)kv8 * 128 +
                       (n & 15) * 8;
    *(short8*)&VT[off] = v;
  }
}

// ---------------------------------------------------------------------------
// Fused flash attention, 2-phase double-buffered pipeline.
// Grid (32, 16) with bijective XCD swizzle (same-head blocks share an XCD L2).
// Per tile: [vmcnt(0) + raw barrier] -> klo reg loads -> stage(t+1) ->
//           QK (hi + x3 from regs) -> defer-max softmax -> patch -> PV.
// K-lo streamed global->reg (saves 8 LDS reads + 12KB LDS); b0..b3 held in
// regs for the x3 correction (saves 8 more LDS reads). LDS 68KB = 2 blk/CU.
// ---------------------------------------------------------------------------
__global__ __launch_bounds__(256, 2) void fa_kernel(
    const short* __restrict__ QChi, const short* __restrict__ QClo,
    const short* __restrict__ KChi, const short* __restrict__ KClo,
    const short* __restrict__ VT, const float* __restrict__ ck,
    const float* __restrict__ tau,
    short* __restrict__ AOmu, short* __restrict__ AOls) {
  __shared__ __attribute__((aligned(16))) short kchi[2][8192];  // 2 x 16KB
  __shared__ __attribute__((aligned(16))) short vt[2][8192];    // 2 x 16KB
  __shared__ __attribute__((aligned(16))) short patch[2048];    // 4 waves x 1KB

  // bijective XCD swizzle: XCD k hosts bids {k, k+8, ...} -> contiguous wg ids
  // -> heads 2k, 2k+1 (K/V working set ~5MB/XCD mostly L2-resident).
  const int bid = blockIdx.x + 32 * blockIdx.y;
  const int wg = ((bid & 7) << 6) + (bid >> 3);
  const int qt = wg & 31;
  const int h = wg >> 5;
  const int tid = threadIdx.x;
  const int lane = tid & 63;
  const int w = tid >> 6;
  const int qgrp = qt * 4 + w;
  const float inv = 1.0f / (fabsf(tau[0]) + 1e-6f);

  const short* QChi_h = QChi + (size_t)h * 524288;
  const short* QClo_h = QClo + (size_t)h * 262144;
  const short* KChi_h = KChi + (size_t)h * 524288;
  const short* KClo_h = KClo + (size_t)h * 262144;
  const short* VT_h = VT + (size_t)h * 524288;
  const float* ckh = ck + (size_t)h * S_LEN;

  // Q fragments in registers
  short8 qhi[8], qlo[4];
#pragma unroll
  for (int ks = 0; ks < 8; ++ks)
    qhi[ks] = *(const short8*)&QChi_h[(size_t)qgrp * 4096 + ks * 512 + lane * 8];
#pragma unroll
  for (int ks = 0; ks < 4; ++ks)
    qlo[ks] = *(const short8*)&QClo_h[(size_t)qgrp * 2048 + ks * 512 + lane * 8];

  floatx4 o[16];
#pragma unroll
  for (int nf = 0; nf < 16; ++nf) o[nf] = 0.0f;
  float m_[4], l_[4];
#pragma unroll
  for (int r = 0; r < 4; ++r) { m_[r] = -1e30f; l_[r] = 0.0f; }

  short* patchw = &patch[w * 512];

  // prologue: stage tile 0 into buffer 0
#pragma unroll
  for (int i = 0; i < 4; ++i) {
    const int c = w * 4 + i;
    gll16(KChi_h + (size_t)(c >> 3) * 4096 + (c & 7) * 512 + lane * 8,
          &kchi[0][c * 512]);
  }
#pragma unroll
  for (int i = 0; i < 4; ++i) {
    const int c = w * 4 + i;
    gll16(VT_h + (size_t)c * 32768 + lane * 8, &vt[0][c * 512]);
  }

  for (int t = 0; t < 64; ++t) {
    const int cur = t & 1;
    // staged loads for buf[cur] are the only outstanding VMEM here (klo of
    // tile t-1 was drained mid-compute): drain + join.
    asm volatile("s_waitcnt vmcnt(0)" ::: "memory");
    __builtin_amdgcn_s_barrier();

    // ---- K-lo register stream for tile t (OLDER than stage -> counted wait)
    short8 klo[8];
#pragma unroll
    for (int j = 0; j < 8; ++j)
      klo[j] = *(const short8*)&KClo_h[(size_t)(2 * t + (j >> 2)) * 2048 +
                                       (j & 3) * 512 + lane * 8];

    // ---- stage tile t+1 into buf[cur^1] (safe: everyone left it at barrier)
    if (t < 63) {
#pragma unroll
      for (int i = 0; i < 4; ++i) {
        const int c = w * 4 + i;
        gll16(KChi_h + (size_t)(2 * (t + 1) + (c >> 3)) * 4096 + (c & 7) * 512 + lane * 8,
              &kchi[cur ^ 1][c * 512]);
      }
#pragma unroll
      for (int i = 0; i < 4; ++i) {
        const int c = w * 4 + i;
        gll16(VT_h + (size_t)c * 32768 + (t + 1) * 512 + lane * 8,
              &vt[cur ^ 1][c * 512]);
      }
    }

    // ---- S = Q·K^T (16q x 32kv); hold b0..b3 halves for the x3 pass ----
    __builtin_amdgcn_s_setprio(1);
    floatx4 s0 = 0.0f, s1 = 0.0f;
    short8 h0[4], h1[4];
#pragma unroll
    for (int ks = 0; ks < 8; ++ks) {
      const short8 b0 = *(const short8*)&kchi[cur][ks * 512 + lane * 8];
      const short8 b1 = *(const short8*)&kchi[cur][(8 + ks) * 512 + lane * 8];
      s0 = __builtin_amdgcn_mfma_f32_16x16x32_bf16(qhi[ks], b0, s0, 0, 0, 0);
      s1 = __builtin_amdgcn_mfma_f32_16x16x32_bf16(qhi[ks], b1, s1, 0, 0, 0);
      if (ks < 4) { h0[ks] = b0; h1[ks] = b1; }
    }
#pragma unroll
    for (int ks = 0; ks < 4; ++ks) {
      s0 = __builtin_amdgcn_mfma_f32_16x16x32_bf16(qhi[ks], klo[ks], s0, 0, 0, 0);
      s1 = __builtin_amdgcn_mfma_f32_16x16x32_bf16(qhi[ks], klo[4 + ks], s1, 0, 0, 0);
      s0 = __builtin_amdgcn_mfma_f32_16x16x32_bf16(qlo[ks], h0[ks], s0, 0, 0, 0);
      s1 = __builtin_amdgcn_mfma_f32_16x16x32_bf16(qlo[ks], h1[ks], s1, 0, 0, 0);
    }
    __builtin_amdgcn_s_setprio(0);

    // ---- softmax: defer-max (THR=8), deferred per-lane sum ----
    const float ck0 = ckh[t * 32 + (lane & 15)];
    const float ck1 = ckh[t * 32 + 16 + (lane & 15)];
    float L0[4], L1[4], p0[4], p1[4];
    bool okl = true;
#pragma unroll
    for (int r = 0; r < 4; ++r) {
      L0[r] = (2.0f * s0[r] - ck0) * inv;
      L1[r] = (2.0f * s1[r] - ck1) * inv;
      okl = okl && (fmaxf(L0[r], L1[r]) <= m_[r] + 8.0f);
    }
    if (__all(okl)) {
#pragma unroll
      for (int r = 0; r < 4; ++r) {
        p0[r] = __expf(L0[r] - m_[r]);
        p1[r] = __expf(L1[r] - m_[r]);
        l_[r] += p0[r] + p1[r];
      }
    } else {
#pragma unroll
      for (int r = 0; r < 4; ++r) {
        float mx = fmaxf(L0[r], L1[r]);
        mx = fmaxf(mx, __shfl_xor(mx, 1));
        mx = fmaxf(mx, __shfl_xor(mx, 2));
        mx = fmaxf(mx, __shfl_xor(mx, 4));
        mx = fmaxf(mx, __shfl_xor(mx, 8));
        const float mnew = fmaxf(m_[r], mx);
        const float alpha = __expf(m_[r] - mnew);
        m_[r] = mnew;
        p0[r] = __expf(L0[r] - mnew);
        p1[r] = __expf(L1[r] - mnew);
        l_[r] = l_[r] * alpha + p0[r] + p1[r];
#pragma unroll
        for (int nf = 0; nf < 16; ++nf) o[nf][r] *= alpha;
      }
    }

    // ---- P (C-layout) -> A-frag layout via wave-private LDS patch ----
    {
      const int row = (lane >> 4) * 4;
      const int c0i = lane & 15;
      const int c1i = 16 + (lane & 15);
#pragma unroll
      for (int r = 0; r < 4; ++r) {
        patchw[(c0i >> 3) * 128 + (row + r) * 8 + (c0i & 7)] = f2bf(p0[r]);
        patchw[(c1i >> 3) * 128 + (row + r) * 8 + (c1i & 7)] = f2bf(p1[r]);
      }
    }
    asm volatile("s_waitcnt lgkmcnt(0)\n" ::: "memory");
    const short8 pa = *(const short8*)&patchw[lane * 8];

    // ---- O += P·V (16q x 256n, K=32) ----
    __builtin_amdgcn_s_setprio(1);
#pragma unroll
    for (int nf = 0; nf < 16; ++nf) {
      const short8 vf = *(const short8*)&vt[cur][nf * 512 + lane * 8];
      o[nf] = __builtin_amdgcn_mfma_f32_16x16x32_bf16(pa, vf, o[nf], 0, 0, 0);
    }
    __builtin_amdgcn_s_setprio(0);
    // no end-of-tile barrier: top-of-next-iter vmcnt(0)+barrier covers WAR.
  }

  // ---- epilogue: cross-lane l reduce, normalize, write AO (linear bf16) ----
  float rs[4];
#pragma unroll
  for (int r = 0; r < 4; ++r) {
    float lv = l_[r];
    lv += __shfl_xor(lv, 1);
    lv += __shfl_xor(lv, 2);
    lv += __shfl_xor(lv, 4);
    lv += __shfl_xor(lv, 8);
    rs[r] = 1.0f / lv;
  }
  const int qbase = qgrp * 16 + (lane >> 4) * 4;
#pragma unroll
  for (int nf = 0; nf < 16; ++nf) {
    const int n = nf * 16 + (lane & 15);
    short* dst = (n < HD) ? AOmu : AOls;
    const int col = h * HD + (n & (HD - 1));
#pragma unroll
    for (int r = 0; r < 4; ++r)
      dst[(size_t)(qbase + r) * HIDDEN + col] = f2bf(o[nf][r] * rs[r]);
  }
}

// ---------------------------------------------------------------------------
extern "C" void kernel_launch(void* const* d_in, const int* in_sizes, int n_in,
                              void* d_out, int out_size, void* d_ws, size_t ws_size,
                              hipStream_t stream) {
  (void)in_sizes; (void)n_in; (void)out_size; (void)ws_size;
  const float* Xmu = (const float*)d_in[0];
  const float* Xls = (const float*)d_in[1];
  const float* cosp = (const float*)d_in[2];
  const float* sinp = (const float*)d_in[3];
  const float* Wq_mu = (const float*)d_in[4];
  const float* Wk_mu = (const float*)d_in[5];
  const float* Wv_mu = (const float*)d_in[6];
  const float* Wo_mu = (const float*)d_in[7];
  const float* Wq_s = (const float*)d_in[8];
  const float* Wk_s = (const float*)d_in[9];
  const float* Wv_s = (const float*)d_in[10];
  const float* Wo_s = (const float*)d_in[11];
  const float* tau = (const float*)d_in[12];

  float* out = (float*)d_out;
  short* S = (short*)d_ws;
  const longlong4 Z4 = {0, 0, 0, 0};
  const long long M4 = (long long)MS(4);

  // 1. conversions
  cvt_all<<<dim3(4096, 1, 10), 256, 0, stream>>>(Xmu, Xls, Wq_mu, Wk_mu, Wv_mu, Wq_s,
                                                 Wk_s, Wv_s, Wo_mu, Wo_s, S);

  // 2. q,k mu projections (x3, full K) -> Y0f/Y1f fp32
  gemm_x3<<<dim3(16, 16, 2), 256, 0, stream>>>(
      S + O_XMU_HI, S + O_XMU_LO, HIDDEN, HIDDEN, Z4, Z4,
      S + O_WQ_HI, S + O_WQ_LO, HIDDEN, HIDDEN, M4, M4, HIDDEN, HIDDEN,
      (float*)(S + O_Y0F), HIDDEN, 4194304);

  // 3. v_mu + sigma projections (plain, z=4) -> Y2..Y5 bf16
  {
    longlong4 ao = {0, (long long)MS(4), (long long)MS(4), (long long)MS(4)};
    gemm_plain<<<dim3(16, 16, 4), 256, 0, stream>>>(
        S + O_XMU_HI, HIDDEN, ao, S + O_WV, HIDDEN, M4, HIDDEN, 2,
        nullptr, HIDDEN, 0, S + O_Y2, M4);
  }

  // 4. build tiled QC/KC + ck, tiled VT
  build_qk<<<dim3(S_LEN, NH), 128, 0, stream>>>(
      (const float*)(S + O_Y0F), (const float*)(S + O_Y1F), S + O_Y3, S + O_Y4,
      cosp, sinp, S + O_QCHI, S + O_QCLO, S + O_KCHI, S + O_KCLO,
      (float*)(S + O_CK));
  build_vt<<<dim3(S_LEN / 32, 256 / 32, NH), 256, 0, stream>>>(S + O_Y2, S + O_Y5,
                                                               S + O_VT);

  // 5. fused flash attention -> AOmu/AOls bf16
  fa_kernel<<<dim3(32, NH), 256, 0, stream>>>(
      S + O_QCHI, S + O_QCLO, S + O_KCHI, S + O_KCLO, S + O_VT,
      (const float*)(S + O_CK), tau, S + O_AOMU, S + O_AOLS);

  // 6. output projections (z=2) -> d_out fp32
  {
    longlong4 ao = {0, (long long)MS(4), 0, 0};
    gemm_plain<<<dim3(16, 16, 2), 256, 0, stream>>>(
        S + O_AOMU, HIDDEN, ao, S + O_WO, HIDDEN, M4, HIDDEN, 0,
        out, HIDDEN, 4194304, nullptr, 0);
  }
}

// Round 3
// 646.468 us; speedup vs baseline: 1.3439x; 1.0668x over previous
//
#include <hip/hip_runtime.h>
#include <hip/hip_bf16.h>

#define S_LEN 2048
#define HIDDEN 2048
#define NH 16
#define HD 128

typedef short short8 __attribute__((ext_vector_type(8)));
typedef short short4_t __attribute__((ext_vector_type(4)));
typedef float floatx4 __attribute__((ext_vector_type(4)));

// ---- ws layout (units of 1M = 1<<20 shorts) ------------------------------
// Phase 1 (cvt_all out / gemm_all in): 0-52
#define MS(x) ((size_t)(x) * (size_t)(1u << 20))
#define O_XMU_HI MS(0)
#define O_XLS_HI MS(4)
#define O_XMU_LO MS(8)
#define O_WQ_HI MS(12)
#define O_WK_HI MS(16)
#define O_WQ_LO MS(20)
#define O_WK_LO MS(24)
#define O_WV MS(28)
#define O_WQS MS(32)
#define O_WKS MS(36)
#define O_WVS MS(40)
#define O_WO MS(44)
#define O_WOS MS(48)
// Phase 2 (gemm_all out / build in): 52-84 — disjoint from 0-52 so the
// merged 6-GEMM launch has no read/write overlay race.
#define O_Y0F MS(52)   // fp32 q proj (8u)
#define O_Y1F MS(60)   // fp32 k proj (8u)
#define O_Y2 MS(68)    // bf16 v_mu (4u)
#define O_Y3 MS(72)    // bf16 qs
#define O_Y4 MS(76)    // bf16 ks
#define O_Y5 MS(80)    // bf16 vs
// Phase 3 (build out / fa in): 84-108 + overlays of dead X/W staging.
#define O_QCHI MS(84)  // tiled [h][qgrp128][k8(32)][q16][8] (8u)
#define O_KCHI MS(92)
#define O_QCLO MS(100) // tiled, K=128 (4u)
#define O_KCLO MS(104)
#define O_VT MS(0)     // tiled [h][ngrp16][kv8(256)][n16][8] (8u, over dead XMU)
#define O_AOMU MS(8)   // bf16 (4u, over dead XMU_LO)
#define O_AOLS MS(12)  // bf16 (4u, over dead WQ_HI)
#define O_CK MS(16)    // fp32 [16][2048] (over dead WK_HI)

__device__ __forceinline__ short f2bf(float f) {
  __hip_bfloat16 h = __float2bfloat16(f);  // RNE
  return __builtin_bit_cast(short, h);
}
__device__ __forceinline__ float bf2f(short s) {
  unsigned u = ((unsigned)(unsigned short)s) << 16;
  return __builtin_bit_cast(float, u);
}

typedef __attribute__((address_space(1))) const unsigned int guint;
typedef __attribute__((address_space(3))) unsigned int luint;
__device__ __forceinline__ void gll16(const void* g, void* l) {
  __builtin_amdgcn_global_load_lds((guint*)g, (luint*)l, 16, 0, 0);
}

// ---------------------------------------------------------------------------
// Conversion pass: fp32 -> bf16 hi (+ lo for z in {0,1,2}).
// ---------------------------------------------------------------------------
__global__ __launch_bounds__(256) void cvt_all(
    const float* __restrict__ xmu, const float* __restrict__ xls,
    const float* __restrict__ wq, const float* __restrict__ wk,
    const float* __restrict__ wv, const float* __restrict__ wqs,
    const float* __restrict__ wks, const float* __restrict__ wvs,
    const float* __restrict__ wo, const float* __restrict__ wos,
    short* __restrict__ Sb) {
  const int z = blockIdx.z;
  const float* src;
  size_t ho;
  size_t lof = (size_t)-1;
  switch (z) {
    case 0: src = xmu; ho = O_XMU_HI; lof = O_XMU_LO; break;
    case 1: src = wq;  ho = O_WQ_HI;  lof = O_WQ_LO;  break;
    case 2: src = wk;  ho = O_WK_HI;  lof = O_WK_LO;  break;
    case 3: src = xls; ho = O_XLS_HI; break;
    case 4: src = wv;  ho = O_WV;  break;
    case 5: src = wqs; ho = O_WQS; break;
    case 6: src = wks; ho = O_WKS; break;
    case 7: src = wvs; ho = O_WVS; break;
    case 8: src = wo;  ho = O_WO;  break;
    default: src = wos; ho = O_WOS; break;
  }
  const size_t i = ((size_t)blockIdx.x * 256 + threadIdx.x) * 4;
  const float4 v = *(const float4*)(src + i);
  short4_t h, l;
  h.x = f2bf(v.x); h.y = f2bf(v.y); h.z = f2bf(v.z); h.w = f2bf(v.w);
  *(short4_t*)(Sb + ho + i) = h;
  if (lof != (size_t)-1) {
    l.x = f2bf(v.x - bf2f(h.x));
    l.y = f2bf(v.y - bf2f(h.y));
    l.z = f2bf(v.z - bf2f(h.z));
    l.w = f2bf(v.w - bf2f(h.w));
    *(short4_t*)(Sb + lof + i) = l;
  }
}

// ---------------------------------------------------------------------------
// Merged projection launch, z=0..5 (1536 blocks -> ~4 blk/CU mix):
//   z=0: q = Xmu·Wq  (x3 split-precision, fp32 out Y0F)
//   z=1: k = Xmu·Wk  (x3, fp32 out Y1F)
//   z=2: v = Xmu·Wv  (plain, bf16 out Y2)
//   z=3..5: qs/ks/vs = Xls·W*s (plain, bf16 out Y3..Y5)
// Inputs live in MS(0-52), outputs in MS(52-84): no overlay race.
// ---------------------------------------------------------------------------
__global__ __launch_bounds__(256) void gemm_all(short* __restrict__ Sb) {
  __shared__ __attribute__((aligned(16))) short As[128 * 32];
  __shared__ __attribute__((aligned(16))) short Bs[128 * 32];
  __shared__ __attribute__((aligned(16))) short Asl[128 * 32];
  __shared__ __attribute__((aligned(16))) short Bsl[128 * 32];
  const int z = blockIdx.z;
  const bool x3 = (z < 2);
  const short* A = Sb + ((z < 3) ? O_XMU_HI : O_XLS_HI);
  const size_t bo = (z == 0) ? O_WQ_HI : (z == 1) ? O_WK_HI : (z == 2) ? O_WV
                   : (z == 3) ? O_WQS : (z == 4) ? O_WKS : O_WVS;
  const short* B = Sb + bo;
  const short* ALo = Sb + O_XMU_LO;
  const short* BLo = Sb + ((z == 0) ? O_WQ_LO : O_WK_LO);
  float* Cf = (float*)(Sb + ((z == 0) ? O_Y0F : O_Y1F));
  short* Cb = Sb + O_Y2 + (size_t)(x3 ? 0 : (z - 2)) * MS(4);

  const int m0 = blockIdx.y * 128, n0 = blockIdx.x * 128;
  const int tid = threadIdx.x, lane = tid & 63, wave = tid >> 6;
  const int wr = wave >> 1, wc = wave & 1;
  const int lr = lane >> 2;
  const int lc = (lane & 3) * 8;
  const int fr = lane & 15, koff = (lane >> 4) * 8;

  floatx4 acc[4][4];
#pragma unroll
  for (int i = 0; i < 4; ++i)
#pragma unroll
    for (int j = 0; j < 4; ++j) acc[i][j] = 0.0f;

  for (int k0 = 0; k0 < HIDDEN; k0 += 32) {
#pragma unroll
    for (int j = 0; j < 2; ++j) {
      const int chunk = j * 4 + wave;
      gll16(A + (size_t)(m0 + chunk * 16 + lr) * HIDDEN + k0 + lc, &As[chunk * 512]);
      gll16(B + (size_t)(n0 + chunk * 16 + lr) * HIDDEN + k0 + lc, &Bs[chunk * 512]);
      if (x3) {
        gll16(ALo + (size_t)(m0 + chunk * 16 + lr) * HIDDEN + k0 + lc, &Asl[chunk * 512]);
        gll16(BLo + (size_t)(n0 + chunk * 16 + lr) * HIDDEN + k0 + lc, &Bsl[chunk * 512]);
      }
    }
    __syncthreads();
    short8 af[4], bf[4], afl[4], bfl[4];
#pragma unroll
    for (int i = 0; i < 4; ++i) {
      af[i] = *(const short8*)&As[(wr * 64 + i * 16 + fr) * 32 + koff];
      if (x3) afl[i] = *(const short8*)&Asl[(wr * 64 + i * 16 + fr) * 32 + koff];
    }
#pragma unroll
    for (int j = 0; j < 4; ++j) {
      bf[j] = *(const short8*)&Bs[(wc * 64 + j * 16 + fr) * 32 + koff];
      if (x3) bfl[j] = *(const short8*)&Bsl[(wc * 64 + j * 16 + fr) * 32 + koff];
    }
#pragma unroll
    for (int i = 0; i < 4; ++i)
#pragma unroll
      for (int j = 0; j < 4; ++j) {
        acc[i][j] = __builtin_amdgcn_mfma_f32_16x16x32_bf16(af[i], bf[j], acc[i][j], 0, 0, 0);
        if (x3) {
          acc[i][j] = __builtin_amdgcn_mfma_f32_16x16x32_bf16(af[i], bfl[j], acc[i][j], 0, 0, 0);
          acc[i][j] = __builtin_amdgcn_mfma_f32_16x16x32_bf16(afl[i], bf[j], acc[i][j], 0, 0, 0);
        }
      }
    __syncthreads();
  }

  const int cr = (lane >> 4) * 4, cc = lane & 15;
#pragma unroll
  for (int i = 0; i < 4; ++i)
#pragma unroll
    for (int j = 0; j < 4; ++j) {
      const int rowb = m0 + wr * 64 + i * 16 + cr;
      const int col = n0 + wc * 64 + j * 16 + cc;
#pragma unroll
      for (int r = 0; r < 4; ++r) {
        const float v = acc[i][j][r];
        if (x3) {
          Cf[(size_t)(rowb + r) * HIDDEN + col] = v;
        } else {
          Cb[(size_t)(rowb + r) * HIDDEN + col] = f2bf(v);
        }
      }
    }
}

// ---------------------------------------------------------------------------
// Plain bf16 GEMM (m97-style), fp32 C out. Used for the final O-projection.
// ---------------------------------------------------------------------------
__global__ __launch_bounds__(256) void gemm_plain(
    const short* __restrict__ Ah, int lda, longlong4 aoff,
    const short* __restrict__ Bh, int ldb, long long strideB,
    int K,
    float* __restrict__ C, int ldc, long long strideC) {
  __shared__ __attribute__((aligned(16))) short As[128 * 32];
  __shared__ __attribute__((aligned(16))) short Bs[128 * 32];
  const int z = blockIdx.z;
  const long long ao = (z == 0) ? aoff.x : (z == 1) ? aoff.y : (z == 2) ? aoff.z : aoff.w;
  const short* A = Ah + ao;
  const short* B = Bh + (long long)z * strideB;
  const int m0 = blockIdx.y * 128, n0 = blockIdx.x * 128;
  const int tid = threadIdx.x, lane = tid & 63, wave = tid >> 6;
  const int wr = wave >> 1, wc = wave & 1;
  const int lr = lane >> 2;
  const int lc = (lane & 3) * 8;
  const int fr = lane & 15, koff = (lane >> 4) * 8;

  floatx4 acc[4][4];
#pragma unroll
  for (int i = 0; i < 4; ++i)
#pragma unroll
    for (int j = 0; j < 4; ++j) acc[i][j] = 0.0f;

  for (int k0 = 0; k0 < K; k0 += 32) {
#pragma unroll
    for (int j = 0; j < 2; ++j) {
      const int chunk = j * 4 + wave;
      gll16(A + (size_t)(m0 + chunk * 16 + lr) * lda + k0 + lc, &As[chunk * 512]);
      gll16(B + (size_t)(n0 + chunk * 16 + lr) * ldb + k0 + lc, &Bs[chunk * 512]);
    }
    __syncthreads();
    short8 af[4], bf[4];
#pragma unroll
    for (int i = 0; i < 4; ++i)
      af[i] = *(const short8*)&As[(wr * 64 + i * 16 + fr) * 32 + koff];
#pragma unroll
    for (int j = 0; j < 4; ++j)
      bf[j] = *(const short8*)&Bs[(wc * 64 + j * 16 + fr) * 32 + koff];
#pragma unroll
    for (int i = 0; i < 4; ++i)
#pragma unroll
      for (int j = 0; j < 4; ++j)
        acc[i][j] = __builtin_amdgcn_mfma_f32_16x16x32_bf16(af[i], bf[j], acc[i][j], 0, 0, 0);
    __syncthreads();
  }

  const int cr = (lane >> 4) * 4, cc = lane & 15;
#pragma unroll
  for (int i = 0; i < 4; ++i)
#pragma unroll
    for (int j = 0; j < 4; ++j) {
      const int rowb = m0 + wr * 64 + i * 16 + cr;
      const int col = n0 + wc * 64 + j * 16 + cc;
#pragma unroll
      for (int r = 0; r < 4; ++r)
        C[(long long)z * strideC + (size_t)(rowb + r) * ldc + col] = acc[i][j][r];
    }
}

// ---------------------------------------------------------------------------
// RoPE + expm1 + QC/KC tiled hi/lo build + ck.
// Tiled layout: elem (s,k) -> grp=(h*128+(s>>4)): grp*K16 + (k>>3)*128 + (s&15)*8 + (k&7)
// ---------------------------------------------------------------------------
__global__ __launch_bounds__(128) void build_qk(
    const float* __restrict__ Yq, const float* __restrict__ Yk,
    const short* __restrict__ Yqs, const short* __restrict__ Yks,
    const float* __restrict__ cosp, const float* __restrict__ sinp,
    short* __restrict__ QChi, short* __restrict__ QClo,
    short* __restrict__ KChi, short* __restrict__ KClo, float* __restrict__ ck) {
  const int s = blockIdx.x;
  const int h = blockIdx.y;
  const int d = threadIdx.x;  // 0..127
  const size_t base = (size_t)s * HIDDEN + h * HD;
  const float c = cosp[s * HD + d];
  const float sn = sinp[s * HD + d];
  const float q = Yq[base + d];
  const float qp = Yq[base + (d ^ 64)];
  const float k = Yk[base + d];
  const float kp = Yk[base + (d ^ 64)];
  const float qr = q * c + ((d < 64) ? -qp : qp) * sn;
  const float kr = k * c + ((d < 64) ? -kp : kp) * sn;
  const float aq = expm1f(0.5f * bf2f(Yqs[base + d]));
  const float ak = expm1f(0.5f * bf2f(Yks[base + d]));
  const size_t grp = (size_t)h * 128 + (s >> 4);
  const int s16 = s & 15;
  const size_t o_hi_d = grp * 4096 + (d >> 3) * 128 + s16 * 8 + (d & 7);
  const size_t o_hi_a = grp * 4096 + ((128 + d) >> 3) * 128 + s16 * 8 + (d & 7);
  const size_t o_lo_d = grp * 2048 + (d >> 3) * 128 + s16 * 8 + (d & 7);
  const short qh = f2bf(qr), kh = f2bf(kr);
  QChi[o_hi_d] = qh;
  QClo[o_lo_d] = f2bf(qr - bf2f(qh));
  QChi[o_hi_a] = f2bf(aq);
  KChi[o_hi_d] = kh;
  KClo[o_lo_d] = f2bf(kr - bf2f(kh));
  KChi[o_hi_a] = f2bf(ak);

  float val = kr * kr + ak * ak;
#pragma unroll
  for (int off = 32; off > 0; off >>= 1) val += __shfl_down(val, off);
  __shared__ float red[2];
  if ((d & 63) == 0) red[d >> 6] = val;
  __syncthreads();
  if (d == 0) ck[(size_t)h * S_LEN + s] = red[0] + red[1];
}

// ---------------------------------------------------------------------------
// VT tiled [h][ngrp16][kv8(256)][n16][8]: n<128 -> v_mu, else v_ls
// ---------------------------------------------------------------------------
__global__ __launch_bounds__(256) void build_vt(const short* __restrict__ Yv,
                                                const short* __restrict__ Yvs,
                                                short* __restrict__ VT) {
  __shared__ short tile[32][33];
  const int s0 = blockIdx.x * 32;
  const int n0 = blockIdx.y * 32;  // never straddles 128
  const int h = blockIdx.z;
  const int tid = threadIdx.x;
  const int tx = tid & 31;
  const int ty = tid >> 5;
  const short* src = (n0 < HD) ? Yv : Yvs;
  const int c0 = n0 & (HD - 1);
#pragma unroll
  for (int r = ty; r < 32; r += 8)
    tile[r][tx] = src[(size_t)(s0 + r) * HIDDEN + h * HD + c0 + tx];
  __syncthreads();
  // 128 chunks: nl (32) x s8 (4); threads 0..127
  if (tid < 128) {
    const int nl = tid >> 2;
    const int s8 = tid & 3;
    short8 v;
#pragma unroll
    for (int e = 0; e < 8; ++e) v[e] = tile[s8 * 8 + e][nl];
    const int n = n0 + nl;
    const int kv8 = (s0 >> 3) + s8;
    const size_t off = (size_t)h * 524288 + (size_t)(n >> 4) * 32768 + (size_t)kv8 * 128 +
                       (n & 15) * 8;
    *(short8*)&VT[off] = v;
  }
}

// ---------------------------------------------------------------------------
// Fused flash attention, 2-phase double-buffered pipeline.
// Grid (32, 16) with bijective XCD swizzle (same-head blocks share an XCD L2).
// Per tile: [vmcnt(0) + raw barrier] -> klo reg loads -> stage(t+1) ->
//           QK (hi + x3 from regs) -> defer-max softmax -> patch -> PV.
// ---------------------------------------------------------------------------
__global__ __launch_bounds__(256, 2) void fa_kernel(
    const short* __restrict__ QChi, const short* __restrict__ QClo,
    const short* __restrict__ KChi, const short* __restrict__ KClo,
    const short* __restrict__ VT, const float* __restrict__ ck,
    const float* __restrict__ tau,
    short* __restrict__ AOmu, short* __restrict__ AOls) {
  __shared__ __attribute__((aligned(16))) short kchi[2][8192];  // 2 x 16KB
  __shared__ __attribute__((aligned(16))) short vt[2][8192];    // 2 x 16KB
  __shared__ __attribute__((aligned(16))) short patch[2048];    // 4 waves x 1KB

  const int bid = blockIdx.x + 32 * blockIdx.y;
  const int wg = ((bid & 7) << 6) + (bid >> 3);
  const int qt = wg & 31;
  const int h = wg >> 5;
  const int tid = threadIdx.x;
  const int lane = tid & 63;
  const int w = tid >> 6;
  const int qgrp = qt * 4 + w;
  const float inv = 1.0f / (fabsf(tau[0]) + 1e-6f);

  const short* QChi_h = QChi + (size_t)h * 524288;
  const short* QClo_h = QClo + (size_t)h * 262144;
  const short* KChi_h = KChi + (size_t)h * 524288;
  const short* KClo_h = KClo + (size_t)h * 262144;
  const short* VT_h = VT + (size_t)h * 524288;
  const float* ckh = ck + (size_t)h * S_LEN;

  short8 qhi[8], qlo[4];
#pragma unroll
  for (int ks = 0; ks < 8; ++ks)
    qhi[ks] = *(const short8*)&QChi_h[(size_t)qgrp * 4096 + ks * 512 + lane * 8];
#pragma unroll
  for (int ks = 0; ks < 4; ++ks)
    qlo[ks] = *(const short8*)&QClo_h[(size_t)qgrp * 2048 + ks * 512 + lane * 8];

  floatx4 o[16];
#pragma unroll
  for (int nf = 0; nf < 16; ++nf) o[nf] = 0.0f;
  float m_[4], l_[4];
#pragma unroll
  for (int r = 0; r < 4; ++r) { m_[r] = -1e30f; l_[r] = 0.0f; }

  short* patchw = &patch[w * 512];

  // prologue: stage tile 0 into buffer 0
#pragma unroll
  for (int i = 0; i < 4; ++i) {
    const int c = w * 4 + i;
    gll16(KChi_h + (size_t)(c >> 3) * 4096 + (c & 7) * 512 + lane * 8,
          &kchi[0][c * 512]);
  }
#pragma unroll
  for (int i = 0; i < 4; ++i) {
    const int c = w * 4 + i;
    gll16(VT_h + (size_t)c * 32768 + lane * 8, &vt[0][c * 512]);
  }

  for (int t = 0; t < 64; ++t) {
    const int cur = t & 1;
    asm volatile("s_waitcnt vmcnt(0)" ::: "memory");
    __builtin_amdgcn_s_barrier();

    // K-lo register stream for tile t
    short8 klo[8];
#pragma unroll
    for (int j = 0; j < 8; ++j)
      klo[j] = *(const short8*)&KClo_h[(size_t)(2 * t + (j >> 2)) * 2048 +
                                       (j & 3) * 512 + lane * 8];

    // stage tile t+1 into buf[cur^1]
    if (t < 63) {
#pragma unroll
      for (int i = 0; i < 4; ++i) {
        const int c = w * 4 + i;
        gll16(KChi_h + (size_t)(2 * (t + 1) + (c >> 3)) * 4096 + (c & 7) * 512 + lane * 8,
              &kchi[cur ^ 1][c * 512]);
      }
#pragma unroll
      for (int i = 0; i < 4; ++i) {
        const int c = w * 4 + i;
        gll16(VT_h + (size_t)c * 32768 + (t + 1) * 512 + lane * 8,
              &vt[cur ^ 1][c * 512]);
      }
    }

    // ---- S = Q·K^T (16q x 32kv); hold b0..b3 halves for the x3 pass ----
    __builtin_amdgcn_s_setprio(1);
    floatx4 s0 = 0.0f, s1 = 0.0f;
    short8 h0[4], h1[4];
#pragma unroll
    for (int ks = 0; ks < 8; ++ks) {
      const short8 b0 = *(const short8*)&kchi[cur][ks * 512 + lane * 8];
      const short8 b1 = *(const short8*)&kchi[cur][(8 + ks) * 512 + lane * 8];
      s0 = __builtin_amdgcn_mfma_f32_16x16x32_bf16(qhi[ks], b0, s0, 0, 0, 0);
      s1 = __builtin_amdgcn_mfma_f32_16x16x32_bf16(qhi[ks], b1, s1, 0, 0, 0);
      if (ks < 4) { h0[ks] = b0; h1[ks] = b1; }
    }
#pragma unroll
    for (int ks = 0; ks < 4; ++ks) {
      s0 = __builtin_amdgcn_mfma_f32_16x16x32_bf16(qhi[ks], klo[ks], s0, 0, 0, 0);
      s1 = __builtin_amdgcn_mfma_f32_16x16x32_bf16(qhi[ks], klo[4 + ks], s1, 0, 0, 0);
      s0 = __builtin_amdgcn_mfma_f32_16x16x32_bf16(qlo[ks], h0[ks], s0, 0, 0, 0);
      s1 = __builtin_amdgcn_mfma_f32_16x16x32_bf16(qlo[ks], h1[ks], s1, 0, 0, 0);
    }
    __builtin_amdgcn_s_setprio(0);

    // ---- softmax: defer-max (THR=8), deferred per-lane sum ----
    const float ck0 = ckh[t * 32 + (lane & 15)];
    const float ck1 = ckh[t * 32 + 16 + (lane & 15)];
    float L0[4], L1[4], p0[4], p1[4];
    bool okl = true;
#pragma unroll
    for (int r = 0; r < 4; ++r) {
      L0[r] = (2.0f * s0[r] - ck0) * inv;
      L1[r] = (2.0f * s1[r] - ck1) * inv;
      okl = okl && (fmaxf(L0[r], L1[r]) <= m_[r] + 8.0f);
    }
    if (__all(okl)) {
#pragma unroll
      for (int r = 0; r < 4; ++r) {
        p0[r] = __expf(L0[r] - m_[r]);
        p1[r] = __expf(L1[r] - m_[r]);
        l_[r] += p0[r] + p1[r];
      }
    } else {
#pragma unroll
      for (int r = 0; r < 4; ++r) {
        float mx = fmaxf(L0[r], L1[r]);
        mx = fmaxf(mx, __shfl_xor(mx, 1));
        mx = fmaxf(mx, __shfl_xor(mx, 2));
        mx = fmaxf(mx, __shfl_xor(mx, 4));
        mx = fmaxf(mx, __shfl_xor(mx, 8));
        const float mnew = fmaxf(m_[r], mx);
        const float alpha = __expf(m_[r] - mnew);
        m_[r] = mnew;
        p0[r] = __expf(L0[r] - mnew);
        p1[r] = __expf(L1[r] - mnew);
        l_[r] = l_[r] * alpha + p0[r] + p1[r];
#pragma unroll
        for (int nf = 0; nf < 16; ++nf) o[nf][r] *= alpha;
      }
    }

    // ---- P (C-layout) -> A-frag layout via wave-private LDS patch ----
    {
      const int row = (lane >> 4) * 4;
      const int c0i = lane & 15;
      const int c1i = 16 + (lane & 15);
#pragma unroll
      for (int r = 0; r < 4; ++r) {
        patchw[(c0i >> 3) * 128 + (row + r) * 8 + (c0i & 7)] = f2bf(p0[r]);
        patchw[(c1i >> 3) * 128 + (row + r) * 8 + (c1i & 7)] = f2bf(p1[r]);
      }
    }
    asm volatile("s_waitcnt lgkmcnt(0)\n" ::: "memory");
    const short8 pa = *(const short8*)&patchw[lane * 8];

    // ---- O += P·V (16q x 256n, K=32) ----
    __builtin_amdgcn_s_setprio(1);
#pragma unroll
    for (int nf = 0; nf < 16; ++nf) {
      const short8 vf = *(const short8*)&vt[cur][nf * 512 + lane * 8];
      o[nf] = __builtin_amdgcn_mfma_f32_16x16x32_bf16(pa, vf, o[nf], 0, 0, 0);
    }
    __builtin_amdgcn_s_setprio(0);
  }

  // ---- epilogue: cross-lane l reduce, normalize, write AO (linear bf16) ----
  float rs[4];
#pragma unroll
  for (int r = 0; r < 4; ++r) {
    float lv = l_[r];
    lv += __shfl_xor(lv, 1);
    lv += __shfl_xor(lv, 2);
    lv += __shfl_xor(lv, 4);
    lv += __shfl_xor(lv, 8);
    rs[r] = 1.0f / lv;
  }
  const int qbase = qgrp * 16 + (lane >> 4) * 4;
#pragma unroll
  for (int nf = 0; nf < 16; ++nf) {
    const int n = nf * 16 + (lane & 15);
    short* dst = (n < HD) ? AOmu : AOls;
    const int col = h * HD + (n & (HD - 1));
#pragma unroll
    for (int r = 0; r < 4; ++r)
      dst[(size_t)(qbase + r) * HIDDEN + col] = f2bf(o[nf][r] * rs[r]);
  }
}

// ---------------------------------------------------------------------------
extern "C" void kernel_launch(void* const* d_in, const int* in_sizes, int n_in,
                              void* d_out, int out_size, void* d_ws, size_t ws_size,
                              hipStream_t stream) {
  (void)in_sizes; (void)n_in; (void)out_size; (void)ws_size;
  const float* Xmu = (const float*)d_in[0];
  const float* Xls = (const float*)d_in[1];
  const float* cosp = (const float*)d_in[2];
  const float* sinp = (const float*)d_in[3];
  const float* Wq_mu = (const float*)d_in[4];
  const float* Wk_mu = (const float*)d_in[5];
  const float* Wv_mu = (const float*)d_in[6];
  const float* Wo_mu = (const float*)d_in[7];
  const float* Wq_s = (const float*)d_in[8];
  const float* Wk_s = (const float*)d_in[9];
  const float* Wv_s = (const float*)d_in[10];
  const float* Wo_s = (const float*)d_in[11];
  const float* tau = (const float*)d_in[12];

  float* out = (float*)d_out;
  short* S = (short*)d_ws;
  const long long M4 = (long long)MS(4);

  // 1. conversions
  cvt_all<<<dim3(4096, 1, 10), 256, 0, stream>>>(Xmu, Xls, Wq_mu, Wk_mu, Wv_mu, Wq_s,
                                                 Wk_s, Wv_s, Wo_mu, Wo_s, S);

  // 2. all six projections in one launch (q,k x3 fp32; v,qs,ks,vs plain bf16)
  gemm_all<<<dim3(16, 16, 6), 256, 0, stream>>>(S);

  // 3. build tiled QC/KC + ck, tiled VT
  build_qk<<<dim3(S_LEN, NH), 128, 0, stream>>>(
      (const float*)(S + O_Y0F), (const float*)(S + O_Y1F), S + O_Y3, S + O_Y4,
      cosp, sinp, S + O_QCHI, S + O_QCLO, S + O_KCHI, S + O_KCLO,
      (float*)(S + O_CK));
  build_vt<<<dim3(S_LEN / 32, 256 / 32, NH), 256, 0, stream>>>(S + O_Y2, S + O_Y5,
                                                               S + O_VT);

  // 4. fused flash attention -> AOmu/AOls bf16
  fa_kernel<<<dim3(32, NH), 256, 0, stream>>>(
      S + O_QCHI, S + O_QCLO, S + O_KCHI, S + O_KCLO, S + O_VT,
      (const float*)(S + O_CK), tau, S + O_AOMU, S + O_AOLS);

  // 5. output projections (z=2) -> d_out fp32
  {
    longlong4 ao = {0, (long long)MS(4), 0, 0};
    gemm_plain<<<dim3(16, 16, 2), 256, 0, stream>>>(
        S + O_AOMU, HIDDEN, ao, S + O_WO, HIDDEN, M4, HIDDEN,
        out, HIDDEN, 4194304);
  }
}